// Round 9
// baseline (69.500 us; speedup 1.0000x reference)
//
#include <hip/hip_runtime.h>
#include <hip/hip_bf16.h>

// FlowNet correlation via bf16 MFMA (gfx950).
// out[b, p*9+o, y, x] = (1/128) sum_c f[b,c,y,x] * s[b,c,y+p-4,x+o-4], zero-pad.
//
// Round 9: traffic-bound fix (rounds 5+8 both hit ~5-6 TB/s L2-read wall).
// kYB 4->8 cuts s-halo amplification 4.5x->3.0x (read bytes -27%).
// Block=(b, 8y, 32x), 512 blocks, 16 waves. wave=(yrow 0..7, half);
// half0={M0N0,M0N1}, half1={M1N1,M1N2}; acc[2][9] f32x4 = 72 VGPR.
// kCP=36: fragment-read lane starts 18*l15 mod 32 all distinct (kCP=40 had
// l15 and l15+8 aliased). Group-XCD swizzle: the 8 x-blocks of one
// (b,y-stripe) land on one XCD -> halo re-reads hit per-XCD L2.

namespace {
constexpr int kC = 128, kH = 128, kW = 256;
constexpr int kWin = 9;
constexpr int kYB = 8, kXB = 32;
constexpr int kSR = kYB + 8;                      // 16 s-rows
constexpr int kSX = kXB + 16;                     // 48 s-cols
constexpr int kCP = 36;                           // padded c-stride (entries)
constexpr int kKC = 32;                           // channels per chunk
constexpr int kNK = kC / kKC;                     // 4
constexpr int kSSz = kSR * kSX * kCP;             // 27648 entries
constexpr int kFSz = kYB * kXB * kCP;             // 9216
constexpr int kSU = kSR * (kSX / 4) * (kKC / 8);  // 768 s staging units
constexpr int kFU = kYB * (kXB / 4) * (kKC / 8);  // 256 f staging units
constexpr int kThreads = 1024;                    // = kSU + kFU, 1 unit/thread
constexpr int kBlocks = 4 * (kH / kYB) * (kW / kXB);  // 512
constexpr int kOS = kYB * kXB + 4;                // 260: OUT_lds per-d stride
constexpr int kLdsE = 81 * kOS * 2;               // 42120 ushorts = 84240 B
constexpr int kCStr = kH * kW;                    // 32768

typedef __attribute__((ext_vector_type(8))) short bf16x8;
typedef __attribute__((ext_vector_type(4))) float f32x4;
}  // namespace

__global__ __launch_bounds__(kThreads) void corr_mfma(
    const float* __restrict__ first,
    const float* __restrict__ second,
    float* __restrict__ out)
{
    __shared__ __align__(16) unsigned short lds[kLdsE];   // 84.2 KB

    const int tid  = threadIdx.x;
    const int lane = tid & 63;
    const int wid  = tid >> 6;          // 0..15
    const int yw   = wid >> 1;          // y-row 0..7
    const int half = wid & 1;           // M-tile 0/1

    // Group-aware XCD swizzle: launch-id % 8 ~ XCD. Blocks on one XCD get
    // consecutive (gi, xt): 8 x-tiles of group g = 8*gi + xcd co-resident.
    const int bid = blockIdx.x;         // 0..511
    const int xcd = bid & 7;
    const int seq = bid >> 3;           // 0..63
    const int xt  = seq & 7;
    const int g   = ((seq >> 3) << 3) + xcd;   // 0..63 = (b, y-stripe)
    const int b   = g >> 4;
    const int y0  = (g & 15) * kYB;
    const int X0  = xt * kXB;

    const size_t ibase = (size_t)b * kC * kCStr;

    // ---- staging role: exactly ONE unit per thread ----
    // unit = (row, x-quad, channel-octet): 8 float4 loads -> 16 cvt_pk -> 4 b128
    const float* ug = nullptr;
    int ul;
    if (tid < kSU) {
        int xq = tid % 12, co = (tid / 12) & 3, row = tid / 48;
        int yg = y0 - 4 + row, xg = X0 - 8 + xq * 4;
        ul = (row * kSX + xq * 4) * kCP + co * 8;
        if (yg >= 0 && yg < kH && xg >= 0 && xg <= kW - 4)
            ug = second + ibase + (size_t)(co * 8) * kCStr + (size_t)yg * kW + xg;
    } else {
        int u2 = tid - kSU;
        int xq = u2 & 7, co = (u2 >> 3) & 3, row = u2 >> 5;
        ul = kSSz + (row * kXB + xq * 4) * kCP + co * 8;
        ug = first + ibase + (size_t)(co * 8) * kCStr
                   + (size_t)(y0 + row) * kW + (X0 + xq * 4);
    }

    float4 pv[8];
    auto issue = [&](int kc) {
        const float4 z = make_float4(0.f, 0.f, 0.f, 0.f);
#pragma unroll
        for (int j = 0; j < 8; ++j) pv[j] = z;
        if (ug) {
            const float* gp = ug + (size_t)kc * kKC * kCStr;
#pragma unroll
            for (int j = 0; j < 8; ++j)
                pv[j] = *(const float4*)(gp + (size_t)j * kCStr);
        }
    };
    auto write_lds = [&]() {
#pragma unroll
        for (int xi = 0; xi < 4; ++xi) {
            union { uint4 q; __hip_bfloat162 h[4]; } pk;
#pragma unroll
            for (int jj = 0; jj < 4; ++jj) {
                float lo = ((const float*)&pv[2 * jj])[xi];
                float hi = ((const float*)&pv[2 * jj + 1])[xi];
                pk.h[jj] = __float22bfloat162_rn(make_float2(lo, hi));
            }
            *(uint4*)&lds[ul + xi * kCP] = pk.q;
        }
    };

    // ---- compute-side fragment offsets ----
    const int l15 = lane & 15, lg = lane >> 4;
    const int aoff  = kSSz + (yw * kXB + half * 16 + l15) * kCP + lg * 8;
    const int boffB = (yw * kSX + half * 16 + l15) * kCP + lg * 8;

    f32x4 acc[2][kWin];
    {
        f32x4 z = {0.f, 0.f, 0.f, 0.f};
#pragma unroll
        for (int j = 0; j < 2; ++j)
#pragma unroll
            for (int p = 0; p < kWin; ++p) acc[j][p] = z;
    }

    // ---- K loop: write(kc) -> issue(kc+1) -> sync -> 18 MFMA -> sync ----
    issue(0);
    for (int kc = 0; kc < kNK; ++kc) {
        write_lds();
        if (kc < kNK - 1) issue(kc + 1);
        __syncthreads();
        bf16x8 a = *(const bf16x8*)&lds[aoff];
#pragma unroll
        for (int j = 0; j < 2; ++j)
#pragma unroll
            for (int p = 0; p < kWin; ++p) {
                bf16x8 bb = *(const bf16x8*)
                    &lds[boffB + j * (16 * kCP) + p * (kSX * kCP)];
                acc[j][p] = __builtin_amdgcn_mfma_f32_16x16x32_bf16(
                    a, bb, acc[j][p], 0, 0, 0);
            }
        __syncthreads();
    }

    // ---- epilogue: band-extract to OUT_lds, then coalesced stores ----
    // D layout: col = l15 (x' within N-tile), row m = 4*lg + r (x in M-tile).
    float* outb = (float*)lds;
    const float inv = 1.0f / (float)kC;
#pragma unroll
    for (int j = 0; j < 2; ++j) {
        const int delta = j ? 12 : -4;     // x' - x + 4 at l15 == m
#pragma unroll
        for (int p = 0; p < kWin; ++p)
#pragma unroll
            for (int r = 0; r < 4; ++r) {
                int m = (lg << 2) + r;
                int o = l15 - m + delta;
                if (o >= 0 && o < kWin) {
                    int d = p * kWin + o;
                    outb[d * kOS + yw * kXB + half * 16 + m] = acc[j][p][r] * inv;
                }
            }
    }
    __syncthreads();

    const size_t ob = (size_t)b * (kWin * kWin) * kCStr;
    for (int i = tid; i < kWin * kWin * kYB * (kXB / 4); i += kThreads) {
        int d = i >> 6;                 // 64 float4 per d (8y x 8xq)
        int r2 = i & 63;
        int yy = r2 >> 3, xq = r2 & 7;
        float4 v = *(const float4*)&outb[d * kOS + yy * kXB + xq * 4];
        *(float4*)&out[ob + ((size_t)d * kH + (y0 + yy)) * kW + X0 + xq * 4] = v;
    }
}

extern "C" void kernel_launch(void* const* d_in, const int* in_sizes, int n_in,
                              void* d_out, int out_size, void* d_ws, size_t ws_size,
                              hipStream_t stream) {
    const float* first  = (const float*)d_in[0];
    const float* second = (const float*)d_in[1];
    float* out = (float*)d_out;
    dim3 grid(kBlocks);      // 512 blocks
    dim3 block(kThreads);    // 1024 threads = 16 waves
    hipLaunchKernelGGL(corr_mfma, grid, block, 0, stream, first, second, out);
}

// Round 10
// 67.133 us; speedup vs baseline: 1.0353x; 1.0353x over previous
//
#include <hip/hip_runtime.h>
#include <hip/hip_bf16.h>

// FlowNet correlation via bf16 MFMA (gfx950).
// out[b, p*9+o, y, x] = (1/128) sum_c f[b,c,y,x] * s[b,c,y+p-4,x+o-4], zero-pad.
//
// Round 10 = round 9 (kYB=8 halo amortization: s-staging amp 4.5x->3.0x)
// with the two confounds removed:
//  - __launch_bounds__(1024,4): VGPR cap 128 (r9's default heuristic capped
//    at 64 -> acc+pv spilled, +120 MB scratch traffic).
//  - kCP=40 (16B-aligned b128 LDS ops) and split epilogue (2 parts, OUT-lds
//    peak 46.8 KB aliased into the 80 KB staging buffer).
// Block=(b, 8y, 32x), 512 blocks, 16 waves = (yrow 0..7) x (M-half);
// half0={M0:N0,N1}, half1={M1:N1,N2}; acc[2][9] f32x4 = 72 VGPR.

namespace {
constexpr int kC = 128, kH = 128, kW = 256;
constexpr int kWin = 9;
constexpr int kYB = 8, kXB = 32;
constexpr int kSR = kYB + 8;                      // 16 s-rows
constexpr int kSX = kXB + 16;                     // 48 s-cols
constexpr int kCP = 40;                           // c-stride (entries), 16B-aligned
constexpr int kKC = 32;                           // channels per chunk
constexpr int kNK = kC / kKC;                     // 4
constexpr int kSSz = kSR * kSX * kCP;             // 30720 entries
constexpr int kFSz = kYB * kXB * kCP;             // 10240
constexpr int kSU = kSR * (kSX / 4) * (kKC / 8);  // 768 s staging units
constexpr int kFU = kYB * (kXB / 4) * (kKC / 8);  // 256 f staging units
constexpr int kThreads = 1024;                    // = kSU + kFU, 1 unit/thread
constexpr int kBlocks = 4 * (kH / kYB) * (kW / kXB);  // 512
constexpr int kOS = kYB * kXB + 4;                // 260: OUT_lds per-d stride
constexpr int kLdsE = kSSz + kFSz;                // 40960 entries = 80 KB
constexpr int kCStr = kH * kW;                    // 32768

typedef __attribute__((ext_vector_type(8))) short bf16x8;
typedef __attribute__((ext_vector_type(4))) float f32x4;
}  // namespace

__global__ __launch_bounds__(kThreads, 4) void corr_mfma(
    const float* __restrict__ first,
    const float* __restrict__ second,
    float* __restrict__ out)
{
    __shared__ __align__(16) unsigned short lds[kLdsE];   // 80 KB

    const int tid  = threadIdx.x;
    const int lane = tid & 63;
    const int wid  = tid >> 6;          // 0..15
    const int yw   = wid >> 1;          // y-row 0..7
    const int half = wid & 1;           // M-tile 0/1

    // Group-aware XCD swizzle: 8 x-tiles of one (b,y-stripe) co-resident/XCD.
    const int bid = blockIdx.x;         // 0..511
    const int xcd = bid & 7;
    const int seq = bid >> 3;           // 0..63
    const int xt  = seq & 7;
    const int g   = ((seq >> 3) << 3) + xcd;   // 0..63 = (b, y-stripe)
    const int b   = g >> 4;
    const int y0  = (g & 15) * kYB;
    const int X0  = xt * kXB;

    const size_t ibase = (size_t)b * kC * kCStr;

    // ---- staging role: exactly ONE unit per thread ----
    // unit = (row, x-quad, channel-octet): 8 float4 loads -> 16 cvt_pk -> 4 b128
    const float* ug = nullptr;
    int ul;
    if (tid < kSU) {
        int xq = tid % 12, co = (tid / 12) & 3, row = tid / 48;
        int yg = y0 - 4 + row, xg = X0 - 8 + xq * 4;
        ul = (row * kSX + xq * 4) * kCP + co * 8;
        if (yg >= 0 && yg < kH && xg >= 0 && xg <= kW - 4)
            ug = second + ibase + (size_t)(co * 8) * kCStr + (size_t)yg * kW + xg;
    } else {
        int u2 = tid - kSU;
        int xq = u2 & 7, co = (u2 >> 3) & 3, row = u2 >> 5;
        ul = kSSz + (row * kXB + xq * 4) * kCP + co * 8;
        ug = first + ibase + (size_t)(co * 8) * kCStr
                   + (size_t)(y0 + row) * kW + (X0 + xq * 4);
    }

    float4 pv[8];
    auto issue = [&](int kc) {
        const float4 z = make_float4(0.f, 0.f, 0.f, 0.f);
#pragma unroll
        for (int j = 0; j < 8; ++j) pv[j] = z;
        if (ug) {
            const float* gp = ug + (size_t)kc * kKC * kCStr;
#pragma unroll
            for (int j = 0; j < 8; ++j)
                pv[j] = *(const float4*)(gp + (size_t)j * kCStr);
        }
    };
    auto write_lds = [&]() {
#pragma unroll
        for (int xi = 0; xi < 4; ++xi) {
            union { uint4 q; __hip_bfloat162 h[4]; } pk;
#pragma unroll
            for (int jj = 0; jj < 4; ++jj) {
                float lo = ((const float*)&pv[2 * jj])[xi];
                float hi = ((const float*)&pv[2 * jj + 1])[xi];
                pk.h[jj] = __float22bfloat162_rn(make_float2(lo, hi));
            }
            *(uint4*)&lds[ul + xi * kCP] = pk.q;
        }
    };

    // ---- compute-side fragment offsets ----
    const int l15 = lane & 15, lg = lane >> 4;
    const int aoff  = kSSz + (yw * kXB + half * 16 + l15) * kCP + lg * 8;
    const int boffB = (yw * kSX + half * 16 + l15) * kCP + lg * 8;

    f32x4 acc[2][kWin];
    {
        f32x4 z = {0.f, 0.f, 0.f, 0.f};
#pragma unroll
        for (int j = 0; j < 2; ++j)
#pragma unroll
            for (int p = 0; p < kWin; ++p) acc[j][p] = z;
    }

    // ---- K loop: write(kc) -> issue(kc+1) -> sync -> 18 MFMA -> sync ----
    issue(0);
    for (int kc = 0; kc < kNK; ++kc) {
        write_lds();
        if (kc < kNK - 1) issue(kc + 1);
        __syncthreads();
        bf16x8 a = *(const bf16x8*)&lds[aoff];
#pragma unroll
        for (int j = 0; j < 2; ++j)
#pragma unroll
            for (int p = 0; p < kWin; ++p) {
                bf16x8 bb = *(const bf16x8*)
                    &lds[boffB + j * (16 * kCP) + p * (kSX * kCP)];
                acc[j][p] = __builtin_amdgcn_mfma_f32_16x16x32_bf16(
                    a, bb, acc[j][p], 0, 0, 0);
            }
        __syncthreads();
    }

    // ---- epilogue: 2 parts (p 0..3 -> 36 planes, p 4..8 -> 45 planes) ----
    // D layout: col = l15 (x' in N-tile), row m = 4*lg + r (x in M-tile).
    float* outb = (float*)lds;
    const float inv = 1.0f / (float)kC;
    const size_t ob = (size_t)b * (kWin * kWin) * kCStr;
#pragma unroll
    for (int part = 0; part < 2; ++part) {
        const int p0 = part ? 4 : 0;
        const int p1 = part ? 9 : 4;
        const int dbase = part ? 36 : 0;
        const int dcnt  = part ? 45 : 36;
#pragma unroll
        for (int j = 0; j < 2; ++j) {
            const int delta = j ? 12 : -4;     // x' - x + 4 at l15 == m
#pragma unroll
            for (int p = p0; p < p1; ++p)
#pragma unroll
                for (int r = 0; r < 4; ++r) {
                    int m = (lg << 2) + r;
                    int o = l15 - m + delta;
                    if (o >= 0 && o < kWin) {
                        int d = p * kWin + o - dbase;
                        outb[d * kOS + yw * kXB + half * 16 + m] =
                            acc[j][p][r] * inv;
                    }
                }
        }
        __syncthreads();
        for (int i = tid; i < dcnt * 64; i += kThreads) {
            int d  = i >> 6;                 // 64 float4 per d (8y x 8xq)
            int r2 = i & 63;
            int yy = r2 >> 3, xq = r2 & 7;
            float4 v = *(const float4*)&outb[d * kOS + yy * kXB + xq * 4];
            *(float4*)&out[ob + ((size_t)(dbase + d) * kH + (y0 + yy)) * kW
                           + X0 + xq * 4] = v;
        }
        if (part == 0) __syncthreads();
    }
}

extern "C" void kernel_launch(void* const* d_in, const int* in_sizes, int n_in,
                              void* d_out, int out_size, void* d_ws, size_t ws_size,
                              hipStream_t stream) {
    const float* first  = (const float*)d_in[0];
    const float* second = (const float*)d_in[1];
    float* out = (float*)d_out;
    dim3 grid(kBlocks);      // 512 blocks
    dim3 block(kThreads);    // 1024 threads = 16 waves
    hipLaunchKernelGGL(corr_mfma, grid, block, 0, stream, first, second, out);
}

// Round 11
// 63.860 us; speedup vs baseline: 1.0883x; 1.0513x over previous
//
#include <hip/hip_runtime.h>
#include <hip/hip_bf16.h>

// FlowNet correlation via bf16 MFMA (gfx950).
// out[b, p*9+o, y, x] = (1/128) sum_c f[b,c,y,x] * s[b,c,y+p-4,x+o-4], zero-pad.
//
// Round 11: latency-bound fix. All MFMA rounds (63-70us) show <15% on every
// pipe with ONE 1024-thread block/CU resident (occupancy pinned at 40%).
// -> smaller independent blocks: tile (b, 4y, 16x), 2048 blocks x 512 thr
// (8 waves), LDS 35.8 KB, acc[9]=36 VGPR => 2 blocks/CU co-resident; their
// barrier convoys interleave. launch_bounds(512,4): VGPR cap 128, NO spill
// (r3/r7/r9/r10 lesson: spill = +65..340 MB WRITE_SIZE, instant regression).
// Wave = (yslot 0..3, N-half). A = F[x][c] (16 x), B = S[c][x'] (32 x').

namespace {
constexpr int kC = 128, kH = 128, kW = 256;
constexpr int kWin = 9;
constexpr int kYB = 4, kXB = 16;
constexpr int kSR = kYB + 8;                      // 12 s-rows
constexpr int kSX = kXB + 16;                     // 32 s-cols (x' span)
constexpr int kCP = 40;                           // c-stride (entries), 16B-aligned
constexpr int kKC = 32;                           // channels per chunk
constexpr int kNK = kC / kKC;                     // 4
constexpr int kSSz = kSR * kSX * kCP;             // 15360 entries
constexpr int kFSz = kYB * kXB * kCP;             // 2560
constexpr int kLdsE = kSSz + kFSz;                // 17920 entries = 35840 B
constexpr int kSU = kSR * (kSX / 4) * (kKC / 8);  // 384 s staging units
constexpr int kFU = kYB * (kXB / 4) * (kKC / 8);  // 64 f staging units
constexpr int kTU = kSU + kFU;                    // 448 (<= 512, 1/thread)
constexpr int kThreads = 512;                     // 8 waves
constexpr int kBlocks = 4 * (kH / kYB) * (kW / kXB);  // 2048
constexpr int kOS = kYB * kXB + 4;                // 68: OUT_lds per-d stride
constexpr int kCStr = kH * kW;                    // 32768

typedef __attribute__((ext_vector_type(8))) short bf16x8;
typedef __attribute__((ext_vector_type(4))) float f32x4;
}  // namespace

__global__ __launch_bounds__(kThreads, 4) void corr_mfma(
    const float* __restrict__ first,
    const float* __restrict__ second,
    float* __restrict__ out)
{
    __shared__ __align__(16) unsigned short lds[kLdsE];   // 35.8 KB

    const int tid  = threadIdx.x;
    const int lane = tid & 63;
    const int wid  = tid >> 6;          // 0..7
    const int yslot = wid >> 1;         // 0..3
    const int Ns    = wid & 1;          // N-half 0/1

    // XCD-grouped bijective swizzle: 2048 = 8 xcd x 256. The 16 x-tiles of a
    // (b, y-stripe) land on one XCD -> s-halo re-reads hit that XCD's L2.
    const int bid = blockIdx.x;
    const int xcd = bid & 7;
    const int seq = bid >> 3;           // 0..255
    const int xt  = seq & 15;
    const int g   = ((seq >> 4) << 3) + xcd;   // 0..127 = (b, y-stripe)
    const int b   = g >> 5;
    const int y0  = (g & 31) * kYB;
    const int X0  = xt * kXB;

    const size_t ibase = (size_t)b * kC * kCStr;

    // ---- staging role: ONE unit per thread (tid < 448) ----
    // unit = (row, x-quad, channel-octet): 8 float4 loads -> 16 cvt_pk -> 4 b128
    const float* ug = nullptr;
    int ul = -1;
    if (tid < kSU) {
        int co = tid & 3, xq = (tid >> 2) & 7, row = tid >> 5;
        int yg = y0 - 4 + row, xg = X0 - 8 + xq * 4;
        ul = (row * kSX + xq * 4) * kCP + co * 8;
        if (yg >= 0 && yg < kH && xg >= 0 && xg <= kW - 4)
            ug = second + ibase + (size_t)(co * 8) * kCStr + (size_t)yg * kW + xg;
    } else if (tid < kTU) {
        int u2 = tid - kSU;
        int co = u2 & 3, xq = (u2 >> 2) & 3, row = u2 >> 4;
        ul = kSSz + (row * kXB + xq * 4) * kCP + co * 8;
        ug = first + ibase + (size_t)(co * 8) * kCStr
                   + (size_t)(y0 + row) * kW + (X0 + xq * 4);
    }

    float4 pv[8];
    auto issue = [&](int kc) {
        if (ul < 0) return;
        const float4 z = make_float4(0.f, 0.f, 0.f, 0.f);
#pragma unroll
        for (int j = 0; j < 8; ++j) pv[j] = z;
        if (ug) {
            const float* gp = ug + (size_t)kc * kKC * kCStr;
#pragma unroll
            for (int j = 0; j < 8; ++j)
                pv[j] = *(const float4*)(gp + (size_t)j * kCStr);
        }
    };
    auto write_lds = [&]() {
        if (ul < 0) return;
#pragma unroll
        for (int xi = 0; xi < 4; ++xi) {
            union { uint4 q; __hip_bfloat162 h[4]; } pk;
#pragma unroll
            for (int jj = 0; jj < 4; ++jj) {
                float lo = ((const float*)&pv[2 * jj])[xi];
                float hi = ((const float*)&pv[2 * jj + 1])[xi];
                pk.h[jj] = __float22bfloat162_rn(make_float2(lo, hi));
            }
            *(uint4*)&lds[ul + xi * kCP] = pk.q;
        }
    };

    // ---- compute-side fragment offsets ----
    const int l15 = lane & 15, lg = lane >> 4;
    const int aoff = kSSz + (yslot * kXB + l15) * kCP + lg * 8;
    const int boff = ((yslot)*kSX + Ns * 16 + l15) * kCP + lg * 8;

    f32x4 acc[kWin];
    {
        f32x4 z = {0.f, 0.f, 0.f, 0.f};
#pragma unroll
        for (int p = 0; p < kWin; ++p) acc[p] = z;
    }

    // ---- K loop: write(kc) -> issue(kc+1) -> sync -> 9 MFMA -> sync ----
    issue(0);
    for (int kc = 0; kc < kNK; ++kc) {
        write_lds();
        if (kc < kNK - 1) issue(kc + 1);
        __syncthreads();
        bf16x8 a = *(const bf16x8*)&lds[aoff];
#pragma unroll
        for (int p = 0; p < kWin; ++p) {
            bf16x8 bb = *(const bf16x8*)&lds[boff + p * (kSX * kCP)];
            acc[p] = __builtin_amdgcn_mfma_f32_16x16x32_bf16(a, bb, acc[p], 0, 0, 0);
        }
        __syncthreads();
    }

    // ---- epilogue: band-extract to OUT_lds (aliases staging), store ----
    // D layout: n = l15 (x' in N-tile), m = 4*lg + r (x in M-tile).
    // o = x' - x + 4 = l15 - m + (Ns ? 12 : -4); valid o in [0,9).
    float* outb = (float*)lds;
    const float inv = 1.0f / (float)kC;
    const int delta = Ns ? 12 : -4;
#pragma unroll
    for (int p = 0; p < kWin; ++p)
#pragma unroll
        for (int r = 0; r < 4; ++r) {
            int m = (lg << 2) + r;
            int o = l15 - m + delta;
            if (o >= 0 && o < kWin) {
                int d = p * kWin + o;
                outb[d * kOS + yslot * kXB + m] = acc[p][r] * inv;
            }
        }
    __syncthreads();

    const size_t ob = (size_t)b * (kWin * kWin) * kCStr;
    for (int i = tid; i < kWin * kWin * kYB * (kXB / 4); i += kThreads) {
        int d  = i >> 4;                 // 16 float4 per d (4y x 4xq)
        int r2 = i & 15;
        int yy = r2 >> 2, xq = r2 & 3;
        float4 v = *(const float4*)&outb[d * kOS + yy * kXB + xq * 4];
        *(float4*)&out[ob + ((size_t)d * kH + (y0 + yy)) * kW + X0 + xq * 4] = v;
    }
}

extern "C" void kernel_launch(void* const* d_in, const int* in_sizes, int n_in,
                              void* d_out, int out_size, void* d_ws, size_t ws_size,
                              hipStream_t stream) {
    const float* first  = (const float*)d_in[0];
    const float* second = (const float*)d_in[1];
    float* out = (float*)d_out;
    dim3 grid(kBlocks);      // 2048 blocks
    dim3 block(kThreads);    // 512 threads = 8 waves
    hipLaunchKernelGGL(corr_mfma, grid, block, 0, stream, first, second, out);
}